// Round 4
// baseline (531.700 us; speedup 1.0000x reference)
//
#include <hip/hip_runtime.h>

#define NPTS   21
#define BATCH  16384
#define ROWS   (BATCH * NPTS)            // 344064 flat (b*21+n) rows
#define NGRP   ((BATCH + 2) / 3)         // 5462 groups of 3 batch elems (63 rows -> pad 64)
#define GPB    4                         // groups per block
#define NBLK   ((NGRP + GPB - 1) / GPB)  // 1366 blocks
#define Z0STR  136                       // zb0 row stride u16 (128+8 pad)
#define Z12STR 264                       // zb12 row stride u16 (256+8 pad)

typedef unsigned short u16;
typedef unsigned int   u32;
typedef __bf16 bf16x8 __attribute__((ext_vector_type(8)));
typedef u16    u16x8  __attribute__((ext_vector_type(8)));
typedef float  f32x4  __attribute__((ext_vector_type(4)));

static __device__ __forceinline__ u16 f2bf(float f) {
  union { float f; u32 u; } v;
  v.f = f;
  u32 r = v.u + 0x7fffu + ((v.u >> 16) & 1u);   // RNE
  return (u16)(r >> 16);
}
static __device__ __forceinline__ float bf2f(u16 u) {
  union { u32 u; float f; } v;
  v.u = ((u32)u) << 16;
  return v.f;
}

// ---- prep: block-diag T1/T2 (bf16 hi+lo split) + transposed bf16 weights ---
__global__ void cheb_prep(const float* __restrict__ adj,
                          const float* __restrict__ weight,   // [3][1][128][128]
                          u16* __restrict__ TBG,              // [2][2][64][64]
                          u16* __restrict__ WtG) {            // [128][384]
  const int tid = threadIdx.x;
  const int gid = blockIdx.x * 256 + tid;
  for (int idx = gid; idx < 128 * 384; idx += 64 * 256) {
    const int d  = idx / 384;
    const int kc = idx - d * 384;              // kc = k*128 + c
    WtG[idx] = f2bf(weight[kc * 128 + d]);
  }
  if (blockIdx.x == 0) {
    __shared__ float Ls[441];
    __shared__ float T2s[441];
    __shared__ float dsi[NPTS];
    if (tid < NPTS) {
      float s = 0.f;
      for (int m = 0; m < NPTS; ++m) s += adj[tid * NPTS + m];
      dsi[tid] = (s > 0.f) ? (1.0f / sqrtf(s)) : 0.f;
    }
    __syncthreads();
    for (int i = tid; i < 441; i += 256) {
      const int n = i / NPTS, m = i - n * NPTS;
      Ls[i] = ((n == m) ? 1.f : 0.f) - dsi[n] * adj[i] * dsi[m];   // T1 = L
    }
    __syncthreads();
    for (int i = tid; i < 441; i += 256) {
      const int n = i / NPTS, m = i - n * NPTS;
      float s = 0.f;
      for (int j = 0; j < NPTS; ++j) s += Ls[n * NPTS + j] * Ls[j * NPTS + m];
      T2s[i] = 2.f * s - ((n == m) ? 1.f : 0.f);                    // T2 = 2L^2 - I
    }
    __syncthreads();
    for (int idx = tid; idx < 2 * 64 * 64; idx += 256) {
      const int k = idx >> 12, rc = idx & 4095, r = rc >> 6, c = rc & 63;
      float v = 0.f;
      if (r < 63 && c < 63 && (r / 21) == (c / 21)) {
        v = (k == 0) ? Ls[(r % 21) * 21 + (c % 21)] : T2s[(r % 21) * 21 + (c % 21)];
      }
      const u16 hi = f2bf(v);
      TBG[(k * 2 + 0) * 4096 + rc] = hi;
      TBG[(k * 2 + 1) * 4096 + rc] = f2bf(v - bf2f(hi));
    }
  }
}

// ---- main: stage -> MFMA mix -> MFMA GEMM, 3 blocks/CU ---------------------
__global__ void __launch_bounds__(256, 3) cheb_main(
    const float* __restrict__ x,      // [16384][21][128] fp32
    const u16*  __restrict__ WtG,     // [128][384] bf16 bits
    const u16*  __restrict__ TBG,     // [2][2][64][64] bf16 bits
    const float* __restrict__ bias,   // [128]
    float* __restrict__ out) {        // [16384][21][128] fp32
  // X tile, row-major, col-swizzled: zb0[r][c ^ 16*((r>>3)&3)]
  __shared__ __align__(16) u16 zb0[64 * Z0STR];    // 17408 B
  // T1x/T2x tile, col-swizzled: zb12[r][j ^ 8*((r>>2)&3)], j = (k-1)*128 + c
  __shared__ __align__(16) u16 zb12[64 * Z12STR];  // 33792 B (total 51200 -> 3 blk/CU)

  const int tid  = threadIdx.x;
  const int wave = tid >> 6;
  const int lane = tid & 63;
  const int quad = lane >> 4;
  const int l15  = lane & 15;

  // persistent B fragments for the output GEMM: wave owns cols [wave*32, +31]
  u16x8 Breg[2][12];
  const int c0 = wave * 32 + l15;
  const int c1 = wave * 32 + 16 + l15;
#pragma unroll
  for (int t = 0; t < 2; ++t) {
    const u16* wp = WtG + (wave * 32 + t * 16 + l15) * 384 + quad * 8;
#pragma unroll
    for (int s = 0; s < 12; ++s) Breg[t][s] = *(const u16x8*)(wp + s * 32);
  }
  const float bias0 = bias[c0];
  const float bias1 = bias[c1];

  const int kk   = wave >> 1;                 // waves 0,1 -> T1; 2,3 -> T2
  const int half = wave & 1;                  // c-half of the mix output

  for (int it = 0; it < GPB; ++it) {
    const int grp = blockIdx.x * GPB + it;
    if (grp >= NGRP) break;                   // uniform across the block
    const int gr0 = grp * 63;                 // first flat row of this group

    __syncthreads();                          // prev group's LDS reads done
    // ---- stage x -> zb0 (bf16, col-swizzled; zeros for pad/OOB rows) ----
#pragma unroll
    for (int i = 0; i < 8; ++i) {
      const int task = i * 256 + tid;         // 64 rows x 32 float4 chunks
      const int r = task >> 5, q = task & 31;
      const int gr = gr0 + r;
      float4 v = make_float4(0.f, 0.f, 0.f, 0.f);
      if (r < 63 && gr < ROWS) v = *(const float4*)(x + (size_t)gr * 128 + q * 4);
      const u32 lo = (u32)f2bf(v.x) | ((u32)f2bf(v.y) << 16);
      const u32 hi = (u32)f2bf(v.z) | ((u32)f2bf(v.w) << 16);
      const int col = (q * 4) ^ (16 * ((r >> 3) & 3));
      *(uint2*)(&zb0[r * Z0STR + col]) = make_uint2(lo, hi);
    }
    __syncthreads();

    // ---- mix via MFMA: zb12[:, kk*128 + cb..] = T_kk @ X ----
    u32 tboff = (u32)(kk * 8192);
#pragma unroll
    for (int nt = 0; nt < 4; ++nt) {
      asm volatile("" : "+v"(tboff));         // keep T loads inside the nt loop (L1 hits)
      const u16* tb = TBG + tboff;
      const int cb  = half * 64 + nt * 16;
      // B-frag column reads from swizzled zb0: key = 16*((m>>3)&3) = 16*quad
      // for both m = quad*8+jj and m = 32+quad*8+jj  -> lane-constant column.
      const int colp = (cb + l15) ^ (16 * quad);
      const u16* zp  = zb0 + quad * 8 * Z0STR + colp;
      u16x8 t0, t1;
#pragma unroll
      for (int jj = 0; jj < 8; ++jj) t0[jj] = zp[jj * Z0STR];
#pragma unroll
      for (int jj = 0; jj < 8; ++jj) t1[jj] = zp[(32 + jj) * Z0STR];
      const bf16x8 bx0 = __builtin_bit_cast(bf16x8, t0);
      const bf16x8 bx1 = __builtin_bit_cast(bf16x8, t1);
      const int colz = (kk * 128 + cb + l15) ^ (8 * quad);  // (row>>2)&3 == quad
#pragma unroll
      for (int mt = 0; mt < 4; ++mt) {
        const int toff = (mt * 16 + l15) * 64 + quad * 8;
        const bf16x8 th0 = __builtin_bit_cast(bf16x8, *(const u16x8*)(tb + toff));
        const bf16x8 tl0 = __builtin_bit_cast(bf16x8, *(const u16x8*)(tb + 4096 + toff));
        const bf16x8 th1 = __builtin_bit_cast(bf16x8, *(const u16x8*)(tb + toff + 32));
        const bf16x8 tl1 = __builtin_bit_cast(bf16x8, *(const u16x8*)(tb + 4096 + toff + 32));
        f32x4 z = {0.f, 0.f, 0.f, 0.f};
        __builtin_amdgcn_s_setprio(1);
        z = __builtin_amdgcn_mfma_f32_16x16x32_bf16(th0, bx0, z, 0, 0, 0);
        z = __builtin_amdgcn_mfma_f32_16x16x32_bf16(tl0, bx0, z, 0, 0, 0);
        z = __builtin_amdgcn_mfma_f32_16x16x32_bf16(th1, bx1, z, 0, 0, 0);
        z = __builtin_amdgcn_mfma_f32_16x16x32_bf16(tl1, bx1, z, 0, 0, 0);
        __builtin_amdgcn_s_setprio(0);
        const int rb = mt * 16 + quad * 4;    // D: row = quad*4+i, col = l15
#pragma unroll
        for (int i = 0; i < 4; ++i)
          zb12[(rb + i) * Z12STR + colz] = f2bf(z[i]);
      }
    }
    __syncthreads();

    // ---- GEMM: 64 rows x this wave's 32 cols, K = 384 ----
    const int swz12q = (quad * 8) ^ (8 * (l15 >> 2));   // (row>>2)&3 == l15>>2
#pragma unroll
    for (int mt = 0; mt < 4; ++mt) {
      f32x4 acc0 = {0.f, 0.f, 0.f, 0.f};
      f32x4 acc1 = {0.f, 0.f, 0.f, 0.f};
      const int row = mt * 16 + l15;
      const u16* z0r = zb0 + row * Z0STR;
      const int a0sw = 16 * ((2 * mt + (l15 >> 3)) & 3);  // (row>>3)&3
      __builtin_amdgcn_s_setprio(1);
#pragma unroll
      for (int s = 0; s < 4; ++s) {           // K 0..127 from zb0
        const bf16x8 a = __builtin_bit_cast(bf16x8,
            *(const u16x8*)(z0r + ((quad * 8 + 32 * s) ^ a0sw)));
        acc0 = __builtin_amdgcn_mfma_f32_16x16x32_bf16(
            a, __builtin_bit_cast(bf16x8, Breg[0][s]), acc0, 0, 0, 0);
        acc1 = __builtin_amdgcn_mfma_f32_16x16x32_bf16(
            a, __builtin_bit_cast(bf16x8, Breg[1][s]), acc1, 0, 0, 0);
      }
      const u16* z12r = zb12 + row * Z12STR + swz12q;
#pragma unroll
      for (int s = 0; s < 8; ++s) {           // K 128..383 from zb12
        const bf16x8 a = __builtin_bit_cast(bf16x8, *(const u16x8*)(z12r + 32 * s));
        acc0 = __builtin_amdgcn_mfma_f32_16x16x32_bf16(
            a, __builtin_bit_cast(bf16x8, Breg[0][4 + s]), acc0, 0, 0, 0);
        acc1 = __builtin_amdgcn_mfma_f32_16x16x32_bf16(
            a, __builtin_bit_cast(bf16x8, Breg[1][4 + s]), acc1, 0, 0, 0);
      }
      __builtin_amdgcn_s_setprio(0);
      const int rbase = mt * 16 + quad * 4;   // D: row = quad*4+reg, col = l15
#pragma unroll
      for (int i = 0; i < 4; ++i) {
        const int r  = rbase + i;
        const int gr = gr0 + r;
        if (r < 63 && gr < ROWS) {
          float* op = out + (size_t)gr * 128;
          op[c0] = acc0[i] + bias0;
          op[c1] = acc1[i] + bias1;
        }
      }
    }
  }
}

extern "C" void kernel_launch(void* const* d_in, const int* in_sizes, int n_in,
                              void* d_out, int out_size, void* d_ws, size_t ws_size,
                              hipStream_t stream) {
  (void)in_sizes; (void)n_in; (void)out_size; (void)ws_size;
  const float* x      = (const float*)d_in[0];
  const float* adj    = (const float*)d_in[1];
  const float* weight = (const float*)d_in[2];
  const float* bias   = (const float*)d_in[3];
  float* out = (float*)d_out;
  u16* TBG = (u16*)d_ws;                        // 32 KB: [2][2][64][64] bf16
  u16* WtG = (u16*)((char*)d_ws + 32768);       // 96 KB: [128][384] bf16
  cheb_prep<<<64, 256, 0, stream>>>(adj, weight, TBG, WtG);
  cheb_main<<<NBLK, 256, 0, stream>>>(x, WtG, TBG, bias, out);
}

// Round 5
// 502.748 us; speedup vs baseline: 1.0576x; 1.0576x over previous
//
#include <hip/hip_runtime.h>

#define NPTS   21
#define BATCH  16384
#define ROWS   (BATCH * NPTS)            // 344064 flat (b*21+n) rows
#define NGRP   ((BATCH + 2) / 3)         // 5462 groups of 3 batch elems (63 rows -> pad 64)
#define GPB    4                         // groups per block
#define NBLK   ((NGRP + GPB - 1) / GPB)  // 1366 blocks
#define Z0STR  136                       // zb0 row stride u16 (128+8 pad)
#define Z12STR 264                       // zb12 row stride u16 (256+8 pad)

typedef unsigned short u16;
typedef unsigned int   u32;
typedef __bf16 bf16x8 __attribute__((ext_vector_type(8)));
typedef u16    u16x8  __attribute__((ext_vector_type(8)));
typedef float  f32x4  __attribute__((ext_vector_type(4)));

static __device__ __forceinline__ u16 f2bf(float f) {
  union { float f; u32 u; } v;
  v.f = f;
  u32 r = v.u + 0x7fffu + ((v.u >> 16) & 1u);   // RNE
  return (u16)(r >> 16);
}
static __device__ __forceinline__ float bf2f(u16 u) {
  union { u32 u; float f; } v;
  v.u = ((u32)u) << 16;
  return v.f;
}

// ---- prep: block-diag T1/T2 (bf16 hi+lo split) + transposed bf16 weights ---
__global__ void cheb_prep(const float* __restrict__ adj,
                          const float* __restrict__ weight,   // [3][1][128][128]
                          u16* __restrict__ TBG,              // [2][2][64][64]
                          u16* __restrict__ WtG) {            // [128][384]
  const int tid = threadIdx.x;
  const int gid = blockIdx.x * 256 + tid;
  for (int idx = gid; idx < 128 * 384; idx += 64 * 256) {
    const int d  = idx / 384;
    const int kc = idx - d * 384;              // kc = k*128 + c
    WtG[idx] = f2bf(weight[kc * 128 + d]);
  }
  if (blockIdx.x == 0) {
    __shared__ float Ls[441];
    __shared__ float T2s[441];
    __shared__ float dsi[NPTS];
    if (tid < NPTS) {
      float s = 0.f;
      for (int m = 0; m < NPTS; ++m) s += adj[tid * NPTS + m];
      dsi[tid] = (s > 0.f) ? (1.0f / sqrtf(s)) : 0.f;
    }
    __syncthreads();
    for (int i = tid; i < 441; i += 256) {
      const int n = i / NPTS, m = i - n * NPTS;
      Ls[i] = ((n == m) ? 1.f : 0.f) - dsi[n] * adj[i] * dsi[m];   // T1 = L
    }
    __syncthreads();
    for (int i = tid; i < 441; i += 256) {
      const int n = i / NPTS, m = i - n * NPTS;
      float s = 0.f;
      for (int j = 0; j < NPTS; ++j) s += Ls[n * NPTS + j] * Ls[j * NPTS + m];
      T2s[i] = 2.f * s - ((n == m) ? 1.f : 0.f);                    // T2 = 2L^2 - I
    }
    __syncthreads();
    for (int idx = tid; idx < 2 * 64 * 64; idx += 256) {
      const int k = idx >> 12, rc = idx & 4095, r = rc >> 6, c = rc & 63;
      float v = 0.f;
      if (r < 63 && c < 63 && (r / 21) == (c / 21)) {
        v = (k == 0) ? Ls[(r % 21) * 21 + (c % 21)] : T2s[(r % 21) * 21 + (c % 21)];
      }
      const u16 hi = f2bf(v);
      TBG[(k * 2 + 0) * 4096 + rc] = hi;
      TBG[(k * 2 + 1) * 4096 + rc] = f2bf(v - bf2f(hi));
    }
  }
}

// ---- main: stage -> MFMA mix -> MFMA GEMM --------------------------------
// __launch_bounds__(256,2): (256,3) made the allocator shrink to 84 VGPR,
// evicting the 96-VGPR persistent Breg set -> inner-loop reloads (R4: 2x slower).
// (256,2) gives ~116 VGPR (R1-measured); occupancy = min(LDS 3, VGPR 4) = 3 blk/CU.
__global__ void __launch_bounds__(256, 2) cheb_main(
    const float* __restrict__ x,      // [16384][21][128] fp32
    const u16*  __restrict__ WtG,     // [128][384] bf16 bits
    const u16*  __restrict__ TBG,     // [2][2][64][64] bf16 bits
    const float* __restrict__ bias,   // [128]
    float* __restrict__ out) {        // [16384][21][128] fp32
  // X tile, row-major, col-swizzled: zb0[r][c ^ 16*((r>>3)&3)]
  __shared__ __align__(16) u16 zb0[64 * Z0STR];    // 17408 B
  // T1x/T2x tile, col-swizzled: zb12[r][j ^ 8*((r>>2)&3)], j = (k-1)*128 + c
  __shared__ __align__(16) u16 zb12[64 * Z12STR];  // 33792 B (total 51200 -> 3 blk/CU)

  const int tid  = threadIdx.x;
  const int wave = tid >> 6;
  const int lane = tid & 63;
  const int quad = lane >> 4;
  const int l15  = lane & 15;

  // persistent B fragments for the output GEMM: wave owns cols [wave*32, +31]
  u16x8 Breg[2][12];
  const int c0 = wave * 32 + l15;
  const int c1 = wave * 32 + 16 + l15;
#pragma unroll
  for (int t = 0; t < 2; ++t) {
    const u16* wp = WtG + (wave * 32 + t * 16 + l15) * 384 + quad * 8;
#pragma unroll
    for (int s = 0; s < 12; ++s) Breg[t][s] = *(const u16x8*)(wp + s * 32);
  }
  const float bias0 = bias[c0];
  const float bias1 = bias[c1];

  const int kk   = wave >> 1;                 // waves 0,1 -> T1; 2,3 -> T2
  const int half = wave & 1;                  // c-half of the mix output

  for (int it = 0; it < GPB; ++it) {
    const int grp = blockIdx.x * GPB + it;
    if (grp >= NGRP) break;                   // uniform across the block
    const int gr0 = grp * 63;                 // first flat row of this group

    __syncthreads();                          // prev group's LDS reads done
    // ---- stage x -> zb0 (bf16, col-swizzled; zeros for pad/OOB rows) ----
#pragma unroll
    for (int i = 0; i < 8; ++i) {
      const int task = i * 256 + tid;         // 64 rows x 32 float4 chunks
      const int r = task >> 5, q = task & 31;
      const int gr = gr0 + r;
      float4 v = make_float4(0.f, 0.f, 0.f, 0.f);
      if (r < 63 && gr < ROWS) v = *(const float4*)(x + (size_t)gr * 128 + q * 4);
      const u32 lo = (u32)f2bf(v.x) | ((u32)f2bf(v.y) << 16);
      const u32 hi = (u32)f2bf(v.z) | ((u32)f2bf(v.w) << 16);
      const int col = (q * 4) ^ (16 * ((r >> 3) & 3));
      *(uint2*)(&zb0[r * Z0STR + col]) = make_uint2(lo, hi);
    }
    __syncthreads();

    // ---- mix via MFMA: zb12[:, kk*128 + cb..] = T_kk @ X ----
    u32 tboff = (u32)(kk * 8192);
#pragma unroll
    for (int nt = 0; nt < 4; ++nt) {
      asm volatile("" : "+v"(tboff));         // keep T loads inside the nt loop (L1 hits)
      const u16* tb = TBG + tboff;
      const int cb  = half * 64 + nt * 16;
      // B-frag column reads from swizzled zb0: key = 16*((m>>3)&3) = 16*quad
      // for both m = quad*8+jj and m = 32+quad*8+jj  -> lane-constant column.
      const int colp = (cb + l15) ^ (16 * quad);
      const u16* zp  = zb0 + quad * 8 * Z0STR + colp;
      u16x8 t0, t1;
#pragma unroll
      for (int jj = 0; jj < 8; ++jj) t0[jj] = zp[jj * Z0STR];
#pragma unroll
      for (int jj = 0; jj < 8; ++jj) t1[jj] = zp[(32 + jj) * Z0STR];
      const bf16x8 bx0 = __builtin_bit_cast(bf16x8, t0);
      const bf16x8 bx1 = __builtin_bit_cast(bf16x8, t1);
      const int colz = (kk * 128 + cb + l15) ^ (8 * quad);  // (row>>2)&3 == quad
#pragma unroll
      for (int mt = 0; mt < 4; ++mt) {
        const int toff = (mt * 16 + l15) * 64 + quad * 8;
        const bf16x8 th0 = __builtin_bit_cast(bf16x8, *(const u16x8*)(tb + toff));
        const bf16x8 tl0 = __builtin_bit_cast(bf16x8, *(const u16x8*)(tb + 4096 + toff));
        const bf16x8 th1 = __builtin_bit_cast(bf16x8, *(const u16x8*)(tb + toff + 32));
        const bf16x8 tl1 = __builtin_bit_cast(bf16x8, *(const u16x8*)(tb + 4096 + toff + 32));
        f32x4 z = {0.f, 0.f, 0.f, 0.f};
        __builtin_amdgcn_s_setprio(1);
        z = __builtin_amdgcn_mfma_f32_16x16x32_bf16(th0, bx0, z, 0, 0, 0);
        z = __builtin_amdgcn_mfma_f32_16x16x32_bf16(tl0, bx0, z, 0, 0, 0);
        z = __builtin_amdgcn_mfma_f32_16x16x32_bf16(th1, bx1, z, 0, 0, 0);
        z = __builtin_amdgcn_mfma_f32_16x16x32_bf16(tl1, bx1, z, 0, 0, 0);
        __builtin_amdgcn_s_setprio(0);
        const int rb = mt * 16 + quad * 4;    // D: row = quad*4+i, col = l15
#pragma unroll
        for (int i = 0; i < 4; ++i)
          zb12[(rb + i) * Z12STR + colz] = f2bf(z[i]);
      }
    }
    __syncthreads();

    // ---- GEMM: 64 rows x this wave's 32 cols, K = 384 ----
    const int swz12q = (quad * 8) ^ (8 * (l15 >> 2));   // (row>>2)&3 == l15>>2
#pragma unroll
    for (int mt = 0; mt < 4; ++mt) {
      f32x4 acc0 = {0.f, 0.f, 0.f, 0.f};
      f32x4 acc1 = {0.f, 0.f, 0.f, 0.f};
      const int row = mt * 16 + l15;
      const u16* z0r = zb0 + row * Z0STR;
      const int a0sw = 16 * ((2 * mt + (l15 >> 3)) & 3);  // (row>>3)&3
      __builtin_amdgcn_s_setprio(1);
#pragma unroll
      for (int s = 0; s < 4; ++s) {           // K 0..127 from zb0
        const bf16x8 a = __builtin_bit_cast(bf16x8,
            *(const u16x8*)(z0r + ((quad * 8 + 32 * s) ^ a0sw)));
        acc0 = __builtin_amdgcn_mfma_f32_16x16x32_bf16(
            a, __builtin_bit_cast(bf16x8, Breg[0][s]), acc0, 0, 0, 0);
        acc1 = __builtin_amdgcn_mfma_f32_16x16x32_bf16(
            a, __builtin_bit_cast(bf16x8, Breg[1][s]), acc1, 0, 0, 0);
      }
      const u16* z12r = zb12 + row * Z12STR + swz12q;
#pragma unroll
      for (int s = 0; s < 8; ++s) {           // K 128..383 from zb12
        const bf16x8 a = __builtin_bit_cast(bf16x8, *(const u16x8*)(z12r + 32 * s));
        acc0 = __builtin_amdgcn_mfma_f32_16x16x32_bf16(
            a, __builtin_bit_cast(bf16x8, Breg[0][4 + s]), acc0, 0, 0, 0);
        acc1 = __builtin_amdgcn_mfma_f32_16x16x32_bf16(
            a, __builtin_bit_cast(bf16x8, Breg[1][4 + s]), acc1, 0, 0, 0);
      }
      __builtin_amdgcn_s_setprio(0);
      const int rbase = mt * 16 + quad * 4;   // D: row = quad*4+reg, col = l15
#pragma unroll
      for (int i = 0; i < 4; ++i) {
        const int r  = rbase + i;
        const int gr = gr0 + r;
        if (r < 63 && gr < ROWS) {
          float* op = out + (size_t)gr * 128;
          op[c0] = acc0[i] + bias0;
          op[c1] = acc1[i] + bias1;
        }
      }
    }
  }
}

extern "C" void kernel_launch(void* const* d_in, const int* in_sizes, int n_in,
                              void* d_out, int out_size, void* d_ws, size_t ws_size,
                              hipStream_t stream) {
  (void)in_sizes; (void)n_in; (void)out_size; (void)ws_size;
  const float* x      = (const float*)d_in[0];
  const float* adj    = (const float*)d_in[1];
  const float* weight = (const float*)d_in[2];
  const float* bias   = (const float*)d_in[3];
  float* out = (float*)d_out;
  u16* TBG = (u16*)d_ws;                        // 32 KB: [2][2][64][64] bf16
  u16* WtG = (u16*)((char*)d_ws + 32768);       // 96 KB: [128][384] bf16
  cheb_prep<<<64, 256, 0, stream>>>(adj, weight, TBG, WtG);
  cheb_main<<<NBLK, 256, 0, stream>>>(x, WtG, TBG, bias, out);
}

// Round 6
// 479.070 us; speedup vs baseline: 1.1099x; 1.0494x over previous
//
#include <hip/hip_runtime.h>

#define NPTS   21
#define BATCH  16384
#define ROWS   (BATCH * NPTS)            // 344064 flat (b*21+n) rows
#define NGRP   ((BATCH + 2) / 3)         // 5462 groups of 3 batch elems (63 rows -> pad 64)
#define GPB    2                         // groups per block
#define NBLK   ((NGRP + GPB - 1) / GPB)  // 2731 blocks
#define ZSTR   392                       // zb row stride in u16 (384+8 pad)
#define XTSTR  72                        // Xt row stride in u16

typedef unsigned short u16;
typedef unsigned int   u32;
typedef __bf16 bf16x8 __attribute__((ext_vector_type(8)));
typedef u16    u16x8  __attribute__((ext_vector_type(8)));
typedef float  f32x4  __attribute__((ext_vector_type(4)));

static __device__ __forceinline__ u16 f2bf(float f) {
  union { float f; u32 u; } v;
  v.f = f;
  u32 r = v.u + 0x7fffu + ((v.u >> 16) & 1u);   // RNE
  return (u16)(r >> 16);
}
static __device__ __forceinline__ float bf2f(u16 u) {
  union { u32 u; float f; } v;
  v.u = ((u32)u) << 16;
  return v.f;
}

// ---- prep: block-diag T1/T2 (bf16 hi+lo split) + transposed bf16 weights ---
__global__ void cheb_prep(const float* __restrict__ adj,
                          const float* __restrict__ weight,   // [3][1][128][128]
                          u16* __restrict__ TBG,              // [2][2][64][64]
                          u16* __restrict__ WtG) {            // [128][384]
  const int tid = threadIdx.x;
  const int gid = blockIdx.x * 256 + tid;
  for (int idx = gid; idx < 128 * 384; idx += 64 * 256) {
    const int d  = idx / 384;
    const int kc = idx - d * 384;              // kc = k*128 + c
    WtG[idx] = f2bf(weight[kc * 128 + d]);
  }
  if (blockIdx.x == 0) {
    __shared__ float Ls[441];
    __shared__ float T2s[441];
    __shared__ float dsi[NPTS];
    if (tid < NPTS) {
      float s = 0.f;
      for (int m = 0; m < NPTS; ++m) s += adj[tid * NPTS + m];
      dsi[tid] = (s > 0.f) ? (1.0f / sqrtf(s)) : 0.f;
    }
    __syncthreads();
    for (int i = tid; i < 441; i += 256) {
      const int n = i / NPTS, m = i - n * NPTS;
      Ls[i] = ((n == m) ? 1.f : 0.f) - dsi[n] * adj[i] * dsi[m];   // T1 = L
    }
    __syncthreads();
    for (int i = tid; i < 441; i += 256) {
      const int n = i / NPTS, m = i - n * NPTS;
      float s = 0.f;
      for (int j = 0; j < NPTS; ++j) s += Ls[n * NPTS + j] * Ls[j * NPTS + m];
      T2s[i] = 2.f * s - ((n == m) ? 1.f : 0.f);                    // T2 = 2L^2 - I
    }
    __syncthreads();
    for (int idx = tid; idx < 2 * 64 * 64; idx += 256) {
      const int k = idx >> 12, rc = idx & 4095, r = rc >> 6, c = rc & 63;
      float v = 0.f;
      if (r < 63 && c < 63 && (r / 21) == (c / 21)) {
        v = (k == 0) ? Ls[(r % 21) * 21 + (c % 21)] : T2s[(r % 21) * 21 + (c % 21)];
      }
      const u16 hi = f2bf(v);
      TBG[(k * 2 + 0) * 4096 + rc] = hi;
      TBG[(k * 2 + 1) * 4096 + rc] = f2bf(v - bf2f(hi));
    }
  }
}

// ---- main: 8-wave block, round-1 data paths, halved per-wave state ---------
// 512 thr, LDS 68608 -> 2 blocks/CU = 16 waves/CU (was 8). Breg = 48 VGPR/wave.
__global__ void __launch_bounds__(512, 4) cheb_main(
    const float* __restrict__ x,      // [16384][21][128] fp32
    const u16*  __restrict__ WtG,     // [128][384] bf16 bits
    const u16*  __restrict__ TBG,     // [2][2][64][64] bf16 bits
    const float* __restrict__ bias,   // [128]
    float* __restrict__ out) {        // [16384][21][128] fp32
  __shared__ __align__(16) u16 zb[64 * ZSTR];     // 50176 B: [X | T1X | T2X]
  __shared__ __align__(16) u16 Xt[128 * XTSTR];   // 18432 B: Xt[c][m ^ key(c)]

  const int tid  = threadIdx.x;
  const int wave = tid >> 6;                  // 0..7
  const int lane = tid & 63;
  const int quad = lane >> 4;
  const int l15  = lane & 15;

  // persistent B fragments: wave owns output cols [wave*16, wave*16+15]
  u16x8 Breg[12];
  const int c0 = wave * 16 + l15;
  {
    const u16* wp = WtG + c0 * 384 + quad * 8;
#pragma unroll
    for (int s = 0; s < 12; ++s) Breg[s] = *(const u16x8*)(wp + s * 32);
  }
  const float bias0 = bias[c0];

  const int kk  = wave >> 2;                  // waves 0-3 -> T1; 4-7 -> T2
  const int qtr = wave & 3;                   // 32-col quarter of the mix output
  const u16* tb = TBG + kk * 8192;

  for (int it = 0; it < GPB; ++it) {
    const int grp = blockIdx.x * GPB + it;
    if (grp >= NGRP) break;                   // uniform across the block
    const int gr0 = grp * 63;                 // first flat row of this group

    __syncthreads();                          // prev group's LDS reads done
    // ---- stage x -> zb[:,0:128] (row-major) AND Xt (transposed, swizzled) --
#pragma unroll
    for (int i = 0; i < 4; ++i) {
      const int task = i * 512 + tid;         // 64 rows x 32 float4 chunks
      const int r = task >> 5, q = task & 31;
      const int gr = gr0 + r;
      float4 v = make_float4(0.f, 0.f, 0.f, 0.f);
      if (r < 63 && gr < ROWS) v = *(const float4*)(x + (size_t)gr * 128 + q * 4);
      const u16 b0 = f2bf(v.x), b1 = f2bf(v.y), b2 = f2bf(v.z), b3 = f2bf(v.w);
      *(uint2*)(&zb[r * ZSTR + q * 4]) =
          make_uint2((u32)b0 | ((u32)b1 << 16), (u32)b2 | ((u32)b3 << 16));
      // transposed copy; XOR-swizzle on m spreads banks; key(c) = 8*((c>>3)&7)
      const int cb4 = q * 4;
      const int rr  = r ^ (8 * ((q >> 1) & 7));
      Xt[(cb4 + 0) * XTSTR + rr] = b0;
      Xt[(cb4 + 1) * XTSTR + rr] = b1;
      Xt[(cb4 + 2) * XTSTR + rr] = b2;
      Xt[(cb4 + 3) * XTSTR + rr] = b3;
    }
    __syncthreads();

    // ---- mix via MFMA: zb[:, (kk+1)*128 + qtr*32 ..] = T_kk @ X ----
#pragma unroll
    for (int nt = 0; nt < 2; ++nt) {
      const int cb  = qtr * 32 + nt * 16;
      const int cc  = cb + l15;
      const int key = 8 * ((cc >> 3) & 7);    // same swizzle as the Xt writes
      const u16* xp = Xt + cc * XTSTR;
      const bf16x8 bx0 = __builtin_bit_cast(bf16x8, *(const u16x8*)(xp + ((quad * 8) ^ key)));
      const bf16x8 bx1 = __builtin_bit_cast(bf16x8, *(const u16x8*)(xp + ((32 + quad * 8) ^ key)));
#pragma unroll
      for (int mt = 0; mt < 4; ++mt) {
        const int toff = (mt * 16 + l15) * 64 + quad * 8;
        const bf16x8 th0 = __builtin_bit_cast(bf16x8, *(const u16x8*)(tb + toff));
        const bf16x8 tl0 = __builtin_bit_cast(bf16x8, *(const u16x8*)(tb + 4096 + toff));
        const bf16x8 th1 = __builtin_bit_cast(bf16x8, *(const u16x8*)(tb + toff + 32));
        const bf16x8 tl1 = __builtin_bit_cast(bf16x8, *(const u16x8*)(tb + 4096 + toff + 32));
        f32x4 z = {0.f, 0.f, 0.f, 0.f};
        __builtin_amdgcn_s_setprio(1);
        z = __builtin_amdgcn_mfma_f32_16x16x32_bf16(th0, bx0, z, 0, 0, 0);
        z = __builtin_amdgcn_mfma_f32_16x16x32_bf16(tl0, bx0, z, 0, 0, 0);
        z = __builtin_amdgcn_mfma_f32_16x16x32_bf16(th1, bx1, z, 0, 0, 0);
        z = __builtin_amdgcn_mfma_f32_16x16x32_bf16(tl1, bx1, z, 0, 0, 0);
        __builtin_amdgcn_s_setprio(0);
        const int rb = mt * 16 + quad * 4;    // D: row = quad*4+i, col = l15
#pragma unroll
        for (int i = 0; i < 4; ++i)
          zb[(rb + i) * ZSTR + (kk + 1) * 128 + cb + l15] = f2bf(z[i]);
      }
    }
    __syncthreads();

    // ---- GEMM: 64 rows x this wave's 16 cols, K = 384 ----
#pragma unroll
    for (int mt = 0; mt < 4; ++mt) {
      f32x4 acc0 = {0.f, 0.f, 0.f, 0.f};
      const u16* zrow = zb + (mt * 16 + l15) * ZSTR + quad * 8;
      __builtin_amdgcn_s_setprio(1);
#pragma unroll
      for (int s = 0; s < 12; ++s) {
        const bf16x8 a = __builtin_bit_cast(bf16x8, *(const u16x8*)(zrow + s * 32));
        acc0 = __builtin_amdgcn_mfma_f32_16x16x32_bf16(
            a, __builtin_bit_cast(bf16x8, Breg[s]), acc0, 0, 0, 0);
      }
      __builtin_amdgcn_s_setprio(0);
      const int rbase = mt * 16 + quad * 4;   // D: row = quad*4+reg, col = l15
#pragma unroll
      for (int i = 0; i < 4; ++i) {
        const int r  = rbase + i;
        const int gr = gr0 + r;
        if (r < 63 && gr < ROWS) {
          out[(size_t)gr * 128 + c0] = acc0[i] + bias0;
        }
      }
    }
  }
}

extern "C" void kernel_launch(void* const* d_in, const int* in_sizes, int n_in,
                              void* d_out, int out_size, void* d_ws, size_t ws_size,
                              hipStream_t stream) {
  (void)in_sizes; (void)n_in; (void)out_size; (void)ws_size;
  const float* x      = (const float*)d_in[0];
  const float* adj    = (const float*)d_in[1];
  const float* weight = (const float*)d_in[2];
  const float* bias   = (const float*)d_in[3];
  float* out = (float*)d_out;
  u16* TBG = (u16*)d_ws;                        // 32 KB: [2][2][64][64] bf16
  u16* WtG = (u16*)((char*)d_ws + 32768);       // 96 KB: [128][384] bf16
  cheb_prep<<<64, 256, 0, stream>>>(adj, weight, TBG, WtG);
  cheb_main<<<NBLK, 512, 0, stream>>>(x, WtG, TBG, bias, out);
}

// Round 8
// 478.349 us; speedup vs baseline: 1.1115x; 1.0015x over previous
//
#include <hip/hip_runtime.h>

#define NPTS   21
#define BATCH  16384
#define ROWS   (BATCH * NPTS)            // 344064 flat (b*21+n) rows
#define NGRP   ((BATCH + 2) / 3)         // 5462 groups of 3 batch elems (63 rows, padded to 64)
#define GPB    2                         // groups per block
#define NBLK   ((NGRP + GPB - 1) / GPB)  // 2731 blocks
#define ZSTR   392                       // zb row stride, u16 units (384 + 8 pad)
#define XTSTR  72                        // Xt row stride, u16 units

typedef unsigned short u16;
typedef unsigned int   u32;
typedef __bf16 bf16x8 __attribute__((ext_vector_type(8)));
typedef u16    u16x8  __attribute__((ext_vector_type(8)));
typedef float  f32x4  __attribute__((ext_vector_type(4)));

static __device__ __forceinline__ u16 f2bf(float f) {
  union { float f; u32 u; } v;
  v.f = f;
  const u32 r = v.u + 0x7fffu + ((v.u >> 16) & 1u);   // round-to-nearest-even
  return (u16)(r >> 16);
}
static __device__ __forceinline__ float bf2f(u16 u) {
  union { u32 u; float f; } v;
  v.u = ((u32)u) << 16;
  return v.f;
}

// ---- prep: block-diag T1/T2 (bf16 hi+lo split) + transposed bf16 weights ---
__global__ void cheb_prep(const float* __restrict__ adj,
                          const float* __restrict__ weight,   // [3][1][128][128]
                          u16* __restrict__ TBG,              // [2][2][64][64]
                          u16* __restrict__ WtG) {            // [128][384]
  const int tid = threadIdx.x;
  const int gid = blockIdx.x * 256 + tid;
  for (int idx = gid; idx < 128 * 384; idx += 64 * 256) {
    const int d  = idx / 384;
    const int kc = idx - d * 384;              // kc = k*128 + c
    WtG[idx] = f2bf(weight[kc * 128 + d]);
  }
  if (blockIdx.x == 0) {
    __shared__ float Ls[441];
    __shared__ float T2s[441];
    __shared__ float dsi[NPTS];
    if (tid < NPTS) {
      float s = 0.f;
      for (int m = 0; m < NPTS; ++m) s += adj[tid * NPTS + m];
      dsi[tid] = (s > 0.f) ? (1.0f / sqrtf(s)) : 0.f;
    }
    __syncthreads();
    for (int i = tid; i < 441; i += 256) {
      const int n = i / NPTS, m = i - n * NPTS;
      Ls[i] = ((n == m) ? 1.f : 0.f) - dsi[n] * adj[i] * dsi[m];   // T1 = L
    }
    __syncthreads();
    for (int i = tid; i < 441; i += 256) {
      const int n = i / NPTS, m = i - n * NPTS;
      float s = 0.f;
      for (int j = 0; j < NPTS; ++j) s += Ls[n * NPTS + j] * Ls[j * NPTS + m];
      T2s[i] = 2.f * s - ((n == m) ? 1.f : 0.f);                    // T2 = 2L^2 - I
    }
    __syncthreads();
    for (int idx = tid; idx < 2 * 64 * 64; idx += 256) {
      const int k = idx >> 12, rc = idx & 4095, r = rc >> 6, c = rc & 63;
      float v = 0.f;
      if (r < 63 && c < 63 && (r / 21) == (c / 21)) {
        const int nn = r % 21, mm = c % 21;
        v = (k == 0) ? Ls[nn * 21 + mm] : T2s[nn * 21 + mm];
      }
      const u16 hi = f2bf(v);
      TBG[(k * 2 + 0) * 4096 + rc] = hi;
      TBG[(k * 2 + 1) * 4096 + rc] = f2bf(v - bf2f(hi));
    }
  }
}

// ---- main: 8-wave block, R1-proven data paths ------------------------------
// waves_per_eu(4,4): with plain __launch_bounds__(512,4) the backend shrank to
// 64 VGPR chasing 8 waves/EU (unreachable: LDS 68.6KB caps 2 blocks/CU), which
// spilled the persistent Breg set (R6: WRITE_SIZE +38MB scratch). min=max=4
// pins the target -> full 128-VGPR budget, no spills, same 16 waves/CU.
__global__ void
__attribute__((amdgpu_flat_work_group_size(512, 512), amdgpu_waves_per_eu(4, 4)))
cheb_main(
    const float* __restrict__ x,      // [16384][21][128] fp32
    const u16*  __restrict__ WtG,     // [128][384] bf16 bits
    const u16*  __restrict__ TBG,     // [2][2][64][64] bf16 bits
    const float* __restrict__ bias,   // [128]
    float* __restrict__ out) {        // [16384][21][128] fp32
  __shared__ __align__(16) u16 zb[64 * ZSTR];     // 50176 B: [X | T1X | T2X]
  __shared__ __align__(16) u16 Xt[128 * XTSTR];   // 18432 B: Xt[c][m ^ key(c)]

  const int tid  = threadIdx.x;
  const int wave = tid >> 6;                  // 0..7
  const int lane = tid & 63;
  const int quad = lane >> 4;
  const int l15  = lane & 15;

  // persistent B fragments: wave owns output cols [wave*16, wave*16+15]
  u16x8 Breg[12];
  const int c0 = wave * 16 + l15;
  {
    const u16* wp = WtG + c0 * 384 + quad * 8;
#pragma unroll
    for (int s = 0; s < 12; ++s) Breg[s] = *(const u16x8*)(wp + s * 32);
  }
  const float bias0 = bias[c0];

  const int kk  = wave >> 2;                  // waves 0-3 -> T1; waves 4-7 -> T2
  const int qtr = wave & 3;                   // 32-col quarter of the mix output
  const u16* tb = TBG + kk * 8192;

  for (int it = 0; it < GPB; ++it) {
    const int grp = blockIdx.x * GPB + it;
    if (grp >= NGRP) break;                   // uniform across the block
    const int gr0 = grp * 63;                 // first flat row of this group

    __syncthreads();                          // prev group's LDS reads done
    // ---- stage x -> zb[:,0:128] (row-major) AND Xt (transposed, swizzled) --
#pragma unroll
    for (int i = 0; i < 4; ++i) {
      const int task = i * 512 + tid;         // 64 rows x 32 float4 chunks
      const int r = task >> 5, q = task & 31;
      const int gr = gr0 + r;
      float4 v = make_float4(0.f, 0.f, 0.f, 0.f);
      if (r < 63 && gr < ROWS) v = *(const float4*)(x + (size_t)gr * 128 + q * 4);
      const u16 b0 = f2bf(v.x), b1 = f2bf(v.y), b2 = f2bf(v.z), b3 = f2bf(v.w);
      *(uint2*)(&zb[r * ZSTR + q * 4]) =
          make_uint2((u32)b0 | ((u32)b1 << 16), (u32)b2 | ((u32)b3 << 16));
      // transposed copy; XOR-swizzle on m spreads banks; key(c) = 8*((c>>3)&7)
      const int cb4 = q * 4;
      const int rr  = r ^ (8 * ((q >> 1) & 7));
      Xt[(cb4 + 0) * XTSTR + rr] = b0;
      Xt[(cb4 + 1) * XTSTR + rr] = b1;
      Xt[(cb4 + 2) * XTSTR + rr] = b2;
      Xt[(cb4 + 3) * XTSTR + rr] = b3;
    }
    __syncthreads();

    // ---- mix via MFMA: zb[:, (kk+1)*128 + qtr*32 ..] = T_kk @ X ----
#pragma unroll
    for (int nt = 0; nt < 2; ++nt) {
      const int cb  = qtr * 32 + nt * 16;
      const int cc  = cb + l15;
      const int key = 8 * ((cc >> 3) & 7);    // matches the Xt write swizzle
      const u16* xp = Xt + cc * XTSTR;
      const bf16x8 bx0 =
          __builtin_bit_cast(bf16x8, *(const u16x8*)(xp + ((quad * 8) ^ key)));
      const bf16x8 bx1 =
          __builtin_bit_cast(bf16x8, *(const u16x8*)(xp + ((32 + quad * 8) ^ key)));
#pragma unroll
      for (int mt = 0; mt < 4; ++mt) {
        const int toff = (mt * 16 + l15) * 64 + quad * 8;
        const bf16x8 th0 = __builtin_bit_cast(bf16x8, *(const u16x8*)(tb + toff));
        const bf16x8 tl0 = __builtin_bit_cast(bf16x8, *(const u16x8*)(tb + 4096 + toff));
        const bf16x8 th1 = __builtin_bit_cast(bf16x8, *(const u16x8*)(tb + toff + 32));
        const bf16x8 tl1 = __builtin_bit_cast(bf16x8, *(const u16x8*)(tb + 4096 + toff + 32));
        f32x4 z = {0.f, 0.f, 0.f, 0.f};
        __builtin_amdgcn_s_setprio(1);
        z = __builtin_amdgcn_mfma_f32_16x16x32_bf16(th0, bx0, z, 0, 0, 0);
        z = __builtin_amdgcn_mfma_f32_16x16x32_bf16(tl0, bx0, z, 0, 0, 0);
        z = __builtin_amdgcn_mfma_f32_16x16x32_bf16(th1, bx1, z, 0, 0, 0);
        z = __builtin_amdgcn_mfma_f32_16x16x32_bf16(tl1, bx1, z, 0, 0, 0);
        __builtin_amdgcn_s_setprio(0);
        const int rb = mt * 16 + quad * 4;    // D: row = quad*4+i, col = l15
#pragma unroll
        for (int i = 0; i < 4; ++i)
          zb[(rb + i) * ZSTR + (kk + 1) * 128 + cb + l15] = f2bf(z[i]);
      }
    }
    __syncthreads();

    // ---- GEMM: 64 rows x this wave's 16 cols, K = 384 ----
#pragma unroll
    for (int mt = 0; mt < 4; ++mt) {
      f32x4 acc0 = {0.f, 0.f, 0.f, 0.f};
      const u16* zrow = zb + (mt * 16 + l15) * ZSTR + quad * 8;
      __builtin_amdgcn_s_setprio(1);
#pragma unroll
      for (int s = 0; s < 12; ++s) {
        const bf16x8 a = __builtin_bit_cast(bf16x8, *(const u16x8*)(zrow + s * 32));
        acc0 = __builtin_amdgcn_mfma_f32_16x16x32_bf16(
            a, __builtin_bit_cast(bf16x8, Breg[s]), acc0, 0, 0, 0);
      }
      __builtin_amdgcn_s_setprio(0);
      const int rbase = mt * 16 + quad * 4;   // D: row = quad*4+reg, col = l15
#pragma unroll
      for (int i = 0; i < 4; ++i) {
        const int r  = rbase + i;
        const int gr = gr0 + r;
        if (r < 63 && gr < ROWS) {
          out[(size_t)gr * 128 + c0] = acc0[i] + bias0;
        }
      }
    }
  }
}

extern "C" void kernel_launch(void* const* d_in, const int* in_sizes, int n_in,
                              void* d_out, int out_size, void* d_ws, size_t ws_size,
                              hipStream_t stream) {
  (void)in_sizes; (void)n_in; (void)out_size; (void)ws_size;
  const float* x      = (const float*)d_in[0];
  const float* adj    = (const float*)d_in[1];
  const float* weight = (const float*)d_in[2];
  const float* bias   = (const float*)d_in[3];
  float* out = (float*)d_out;
  u16* TBG = (u16*)d_ws;                        // 32 KB: [2][2][64][64] bf16
  u16* WtG = (u16*)((char*)d_ws + 32768);       // 96 KB: [128][384] bf16
  cheb_prep<<<64, 256, 0, stream>>>(adj, weight, TBG, WtG);
  cheb_main<<<NBLK, 512, 0, stream>>>(x, WtG, TBG, bias, out);
}